// Round 1
// 1117.570 us; speedup vs baseline: 1.0378x; 1.0378x over previous
//
#include <hip/hip_runtime.h>
#include <hip/hip_bf16.h>
#include <stdint.h>

#define T_TOK 8192
#define HID 1024
#define FFN_D 4096
#define NE 8
#define NPAIR 16384
#define NPAIR_PAD 16512
#define MAXMB 136

typedef _Float16 h8 __attribute__((ext_vector_type(8)));
typedef _Float16 h4 __attribute__((ext_vector_type(4)));
typedef float v4f __attribute__((ext_vector_type(4)));

__device__ __forceinline__ void async16(const void* g, void* l) {
  auto gp = (const __attribute__((address_space(1))) uint32_t*)(uintptr_t)g;
  auto lp = (__attribute__((address_space(3))) uint32_t*)(uintptr_t)l;
  __builtin_amdgcn_global_load_lds(gp, lp, 16, 0, 0);
}

// ---------------- router: logits -> softmax -> top2 ----------------
__global__ void k_router(const float* __restrict__ x, const float* __restrict__ Wr,
                         int2* __restrict__ re, float2* __restrict__ rs,
                         int* __restrict__ counts) {
  int lane = threadIdx.x & 63;
  int t = blockIdx.x * 4 + (threadIdx.x >> 6);
  const float* xt = x + (size_t)t * HID;
  float acc[NE];
#pragma unroll
  for (int e = 0; e < NE; ++e) acc[e] = 0.f;
  for (int i = 0; i < HID / 64; ++i) {
    float xv = xt[lane + 64 * i];
#pragma unroll
    for (int e = 0; e < NE; ++e) acc[e] += xv * Wr[e * HID + lane + 64 * i];
  }
#pragma unroll
  for (int e = 0; e < NE; ++e) {
    float v = acc[e];
#pragma unroll
    for (int off = 32; off > 0; off >>= 1) v += __shfl_down(v, off);
    acc[e] = v;
  }
  if (lane == 0) {
    float mx = acc[0];
#pragma unroll
    for (int e = 1; e < NE; ++e) mx = fmaxf(mx, acc[e]);
    float p[NE];
    float sum = 0.f;
#pragma unroll
    for (int e = 0; e < NE; ++e) { p[e] = __expf(acc[e] - mx); sum += p[e]; }
    float inv = 1.f / sum;
    int e0 = 0; float b0 = p[0];
#pragma unroll
    for (int e = 1; e < NE; ++e) if (p[e] > b0) { b0 = p[e]; e0 = e; }
    int e1 = -1; float b1v = -1.f;
#pragma unroll
    for (int e = 0; e < NE; ++e) if (e != e0 && p[e] > b1v) { b1v = p[e]; e1 = e; }
    re[t] = make_int2(e0, e1);
    rs[t] = make_float2(b0 * inv, b1v * inv);
    atomicAdd(&counts[e0], 1);
    atomicAdd(&counts[e1], 1);
  }
}

// ---------------- plan: per-expert offsets + m-block table ----------------
__global__ void k_plan(const int* __restrict__ counts, int* __restrict__ offsets,
                       int* __restrict__ cursors, int* __restrict__ nmb,
                       int* __restrict__ bexp, int* __restrict__ brow0,
                       int* __restrict__ brows) {
  if (threadIdx.x == 0 && blockIdx.x == 0) {
    int off = 0, mb = 0;
    for (int e = 0; e < NE; ++e) {
      offsets[e] = off;
      cursors[e] = off;
      int c = counts[e];
      int nb = (c + 127) >> 7;
      for (int b = 0; b < nb; ++b) {
        bexp[mb] = e;
        brow0[mb] = off + b * 128;
        int r = c - b * 128;
        brows[mb] = r < 128 ? r : 128;
        ++mb;
      }
      off += c;
    }
    *nmb = mb;
  }
}

// ---------------- scatter pairs into expert-sorted order ----------------
// NOTE: ppos aliases the rs region (rs is dead after this kernel). rs/ppos
// intentionally NOT __restrict__; s is loaded before any ppos store.
__global__ void k_scatter(const int2* __restrict__ re, float2* rs,
                          int* __restrict__ cursors, int* __restrict__ ptok,
                          float* __restrict__ pw, int* ppos) {
  int t = blockIdx.x * 256 + threadIdx.x;
  if (t >= T_TOK) return;
  int2 e = re[t];
  float2 s = rs[t];
  int p0 = atomicAdd(&cursors[e.x], 1);
  ptok[p0] = t; pw[p0] = s.x;
  int p1 = atomicAdd(&cursors[e.y], 1);
  ptok[p1] = t; pw[p1] = s.y;
  ppos[2 * t] = p0;
  ppos[2 * t + 1] = p1;
}

// ---------------- gather tokens into A (f16) ----------------
__global__ void k_gather(const float* __restrict__ x, const int* __restrict__ ptok,
                         _Float16* __restrict__ A) {
  int lane = threadIdx.x & 63;
  int p = blockIdx.x * 4 + (threadIdx.x >> 6);
  int t = ptok[p];
  const float4* src = (const float4*)(x + (size_t)t * HID);
  h4* dst = (h4*)(A + (size_t)p * HID);
#pragma unroll
  for (int i = 0; i < 4; ++i) {
    float4 v = src[lane + 64 * i];
    h4 h;
    h[0] = (_Float16)v.x; h[1] = (_Float16)v.y;
    h[2] = (_Float16)v.z; h[3] = (_Float16)v.w;
    dst[lane + 64 * i] = h;
  }
}

// ---------------- elementwise f32 -> f16 cast ----------------
__global__ void k_cast(const float* __restrict__ src, _Float16* __restrict__ dst, int n4) {
  int i = blockIdx.x * blockDim.x + threadIdx.x;
  int stride = gridDim.x * blockDim.x;
  const float4* s = (const float4*)src;
  h4* d = (h4*)dst;
  for (; i < n4; i += stride) {
    float4 v = s[i];
    h4 h;
    h[0] = (_Float16)v.x; h[1] = (_Float16)v.y;
    h[2] = (_Float16)v.z; h[3] = (_Float16)v.w;
    d[i] = h;
  }
}

// LDS chunk-position swizzle: logical k-chunk c of row r stored at position
// (c + (r>>1)) & 3. Makes each consecutive-8-lane group of the b128 fragment
// read cover all 8 bank quads exactly once (was 8-way conflicted: row stride
// 64 B = 16 banks). Staging swizzles the GLOBAL source address instead of the
// LDS dest (global_load_lds requires contiguous lane->LDS mapping).
#define SWZ_POS(r, c) (((c) + ((r) >> 1)) & 3)
#define SWZ_CHUNK(r, p) (((p) - ((r) >> 1)) & 3)

// ---------------- fc1: A[pairs,HID] @ W1[e]^T + b1 -> silu -> hmid f16 ----------------
__global__ __launch_bounds__(256) void k_fc1(
    const _Float16* __restrict__ A, const _Float16* __restrict__ W1h,
    const float* __restrict__ b1, _Float16* __restrict__ hmid,
    const int* __restrict__ nmb, const int* __restrict__ bexp,
    const int* __restrict__ brow0, const int* __restrict__ brows) {
  int mb = blockIdx.y;
  if (mb >= *nmb) return;
  int e = bexp[mb];
  int row0 = brow0[mb];
  int rows = brows[mb];
  int n0 = blockIdx.x * 128;

  __shared__ _Float16 As[128 * 32];
  __shared__ _Float16 Bs[128 * 32];

  int tid = threadIdx.x;
  int lane = tid & 63;
  int wave = tid >> 6;
  int wr = (wave >> 1) * 64;
  int wc = (wave & 1) * 64;
  int lrow = lane & 15;
  int lq = lane >> 4;

  const _Float16* Wb = W1h + (size_t)e * FFN_D * HID;

  v4f acc[4][4];
  v4f z = {0.f, 0.f, 0.f, 0.f};
#pragma unroll
  for (int i = 0; i < 4; ++i)
#pragma unroll
    for (int j = 0; j < 4; ++j) acc[i][j] = z;

  for (int k0 = 0; k0 < HID; k0 += 32) {
#pragma unroll
    for (int r = 0; r < 2; ++r) {
      int c = r * 256 + tid;
      int row = c >> 2, pos = c & 3;
      async16(A + (size_t)(row0 + row) * HID + k0 + SWZ_CHUNK(row, pos) * 8, &As[c * 8]);
    }
#pragma unroll
    for (int r = 0; r < 2; ++r) {
      int c = r * 256 + tid;
      int row = c >> 2, pos = c & 3;
      async16(Wb + (size_t)(n0 + row) * HID + k0 + SWZ_CHUNK(row, pos) * 8, &Bs[c * 8]);
    }
    __syncthreads();
    h8 af[4], bf[4];
#pragma unroll
    for (int i = 0; i < 4; ++i) {
      int row = wr + i * 16 + lrow;
      af[i] = *(const h8*)&As[row * 32 + SWZ_POS(row, lq) * 8];
    }
#pragma unroll
    for (int j = 0; j < 4; ++j) {
      int row = wc + j * 16 + lrow;
      bf[j] = *(const h8*)&Bs[row * 32 + SWZ_POS(row, lq) * 8];
    }
#pragma unroll
    for (int i = 0; i < 4; ++i)
#pragma unroll
      for (int j = 0; j < 4; ++j)
        acc[i][j] = __builtin_amdgcn_mfma_f32_16x16x32_f16(af[i], bf[j], acc[i][j], 0, 0, 0);
    __syncthreads();
  }

#pragma unroll
  for (int j = 0; j < 4; ++j) {
    int gcol = n0 + wc + j * 16 + lrow;
    float bias = b1[e * FFN_D + gcol];
#pragma unroll
    for (int i = 0; i < 4; ++i) {
#pragma unroll
      for (int r = 0; r < 4; ++r) {
        int grow = wr + i * 16 + lq * 4 + r;
        if (grow < rows) {
          float v = acc[i][j][r] + bias;
          float sv = v / (1.f + __expf(-v));
          hmid[(size_t)(row0 + grow) * FFN_D + gcol] = (_Float16)sv;
        }
      }
    }
  }
}

// ---------------- fc2: hmid @ W2[e]^T + b2, weighted PLAIN store to pairout ----------------
__global__ __launch_bounds__(256) void k_fc2(
    const _Float16* __restrict__ hmid, const _Float16* __restrict__ W2h,
    const float* __restrict__ b2, const float* __restrict__ pw,
    float* __restrict__ pairout,
    const int* __restrict__ nmb, const int* __restrict__ bexp,
    const int* __restrict__ brow0, const int* __restrict__ brows) {
  int mb = blockIdx.y;
  if (mb >= *nmb) return;
  int e = bexp[mb];
  int row0 = brow0[mb];
  int rows = brows[mb];
  int n0 = blockIdx.x * 128;

  __shared__ _Float16 As[128 * 32];
  __shared__ _Float16 Bs[128 * 32];

  int tid = threadIdx.x;
  int lane = tid & 63;
  int wave = tid >> 6;
  int wr = (wave >> 1) * 64;
  int wc = (wave & 1) * 64;
  int lrow = lane & 15;
  int lq = lane >> 4;

  const _Float16* Wb = W2h + (size_t)e * HID * FFN_D;

  v4f acc[4][4];
  v4f z = {0.f, 0.f, 0.f, 0.f};
#pragma unroll
  for (int i = 0; i < 4; ++i)
#pragma unroll
    for (int j = 0; j < 4; ++j) acc[i][j] = z;

  for (int k0 = 0; k0 < FFN_D; k0 += 32) {
#pragma unroll
    for (int r = 0; r < 2; ++r) {
      int c = r * 256 + tid;
      int row = c >> 2, pos = c & 3;
      async16(hmid + (size_t)(row0 + row) * FFN_D + k0 + SWZ_CHUNK(row, pos) * 8, &As[c * 8]);
    }
#pragma unroll
    for (int r = 0; r < 2; ++r) {
      int c = r * 256 + tid;
      int row = c >> 2, pos = c & 3;
      async16(Wb + (size_t)(n0 + row) * FFN_D + k0 + SWZ_CHUNK(row, pos) * 8, &Bs[c * 8]);
    }
    __syncthreads();
    h8 af[4], bf[4];
#pragma unroll
    for (int i = 0; i < 4; ++i) {
      int row = wr + i * 16 + lrow;
      af[i] = *(const h8*)&As[row * 32 + SWZ_POS(row, lq) * 8];
    }
#pragma unroll
    for (int j = 0; j < 4; ++j) {
      int row = wc + j * 16 + lrow;
      bf[j] = *(const h8*)&Bs[row * 32 + SWZ_POS(row, lq) * 8];
    }
#pragma unroll
    for (int i = 0; i < 4; ++i)
#pragma unroll
      for (int j = 0; j < 4; ++j)
        acc[i][j] = __builtin_amdgcn_mfma_f32_16x16x32_f16(af[i], bf[j], acc[i][j], 0, 0, 0);
    __syncthreads();
  }

#pragma unroll
  for (int j = 0; j < 4; ++j) {
    int gcol = n0 + wc + j * 16 + lrow;
    float bias = b2[e * HID + gcol];
#pragma unroll
    for (int i = 0; i < 4; ++i) {
#pragma unroll
      for (int r = 0; r < 4; ++r) {
        int grow = wr + i * 16 + lq * 4 + r;
        if (grow < rows) {
          int row = row0 + grow;
          float w = pw[row];
          pairout[(size_t)row * HID + gcol] = w * (acc[i][j][r] + bias);
        }
      }
    }
  }
}

// ---------------- combine: out[t] = pairout[p0(t)] + pairout[p1(t)] ----------------
// one block per token; p0/p1 are block-uniform (scalar broadcast loads)
__global__ void k_combine(const float* __restrict__ pairout, const int* __restrict__ ppos,
                          float* __restrict__ out) {
  int t = blockIdx.x;
  int c = threadIdx.x;
  int p0 = ppos[2 * t];
  int p1 = ppos[2 * t + 1];
  const float4* a = (const float4*)(pairout + (size_t)p0 * HID);
  const float4* b = (const float4*)(pairout + (size_t)p1 * HID);
  float4 va = a[c];
  float4 vb = b[c];
  float4 o;
  o.x = va.x + vb.x; o.y = va.y + vb.y; o.z = va.z + vb.z; o.w = va.w + vb.w;
  ((float4*)(out + (size_t)t * HID))[c] = o;
}

extern "C" void kernel_launch(void* const* d_in, const int* in_sizes, int n_in,
                              void* d_out, int out_size, void* d_ws, size_t ws_size,
                              hipStream_t stream) {
  const float* x  = (const float*)d_in[0];
  const float* Wr = (const float*)d_in[1];
  const float* W1 = (const float*)d_in[2];
  const float* b1 = (const float*)d_in[3];
  const float* W2 = (const float*)d_in[4];
  const float* b2 = (const float*)d_in[5];
  float* out = (float*)d_out;

  uint8_t* ws = (uint8_t*)d_ws;
  int* meta    = (int*)ws;
  int* counts  = meta;        // 8
  int* cursors = meta + 8;    // 8
  int* offsets = meta + 16;   // 8
  int* nmb     = meta + 24;   // 1
  int* bexp    = meta + 32;   // 160
  int* brow0   = meta + 192;  // 160
  int* brows   = meta + 352;  // 160
  int2*   re   = (int2*)(ws + 4096);
  float2* rs   = (float2*)(ws + 69632);
  int*    ppos = (int*)(ws + 69632);             // aliases rs (rs dead after k_scatter)
  int*    ptok = (int*)(ws + 135168);
  float*  pw   = (float*)(ws + 201216);
  _Float16* A    = (_Float16*)(ws + 267264);     // [16512,1024]
  _Float16* W1h  = (_Float16*)(ws + 34083840);   // [8,4096,1024]
  float* pairout = (float*)(ws + 34083840);      // [16384,1024] f32, aliases W1h (dead after fc1)
  _Float16* W2h  = (_Float16*)(ws + 101192704);  // [8,1024,4096]
  _Float16* hmid = (_Float16*)(ws + 168301568);  // [16512,4096]

  hipMemsetAsync(ws, 0, 4096, stream);

  k_router<<<T_TOK / 4, 256, 0, stream>>>(x, Wr, re, rs, counts);
  k_plan<<<1, 64, 0, stream>>>(counts, offsets, cursors, nmb, bexp, brow0, brows);
  k_scatter<<<T_TOK / 256, 256, 0, stream>>>(re, rs, cursors, ptok, pw, ppos);
  k_gather<<<NPAIR / 4, 256, 0, stream>>>(x, ptok, A);
  k_cast<<<2048, 256, 0, stream>>>(W1, W1h, NE * FFN_D * HID / 4);
  k_cast<<<2048, 256, 0, stream>>>(W2, W2h, NE * HID * FFN_D / 4);
  k_fc1<<<dim3(FFN_D / 128, MAXMB), 256, 0, stream>>>(A, W1h, b1, hmid, nmb, bexp, brow0, brows);
  k_fc2<<<dim3(HID / 128, MAXMB), 256, 0, stream>>>(hmid, W2h, b2, pw, pairout, nmb, bexp, brow0, brows);
  k_combine<<<T_TOK, 256, 0, stream>>>(pairout, ppos, out);
}

// Round 3
// 1070.856 us; speedup vs baseline: 1.0830x; 1.0436x over previous
//
#include <hip/hip_runtime.h>
#include <hip/hip_bf16.h>
#include <stdint.h>

#define T_TOK 8192
#define HID 1024
#define FFN_D 4096
#define NE 8
#define NPAIR 16384
#define NPAIR_PAD 16512
#define MAXMB 136

typedef _Float16 h8 __attribute__((ext_vector_type(8)));
typedef _Float16 h4 __attribute__((ext_vector_type(4)));
typedef float v4f __attribute__((ext_vector_type(4)));

__device__ __forceinline__ void async16(const void* g, void* l) {
  auto gp = (const __attribute__((address_space(1))) uint32_t*)(uintptr_t)g;
  auto lp = (__attribute__((address_space(3))) uint32_t*)(uintptr_t)l;
  __builtin_amdgcn_global_load_lds(gp, lp, 16, 0, 0);
}

// ---------------- router: logits -> softmax -> top2 ----------------
__global__ void k_router(const float* __restrict__ x, const float* __restrict__ Wr,
                         int2* __restrict__ re, float2* __restrict__ rs,
                         int* __restrict__ counts) {
  int lane = threadIdx.x & 63;
  int t = blockIdx.x * 4 + (threadIdx.x >> 6);
  const float* xt = x + (size_t)t * HID;
  float acc[NE];
#pragma unroll
  for (int e = 0; e < NE; ++e) acc[e] = 0.f;
  for (int i = 0; i < HID / 64; ++i) {
    float xv = xt[lane + 64 * i];
#pragma unroll
    for (int e = 0; e < NE; ++e) acc[e] += xv * Wr[e * HID + lane + 64 * i];
  }
#pragma unroll
  for (int e = 0; e < NE; ++e) {
    float v = acc[e];
#pragma unroll
    for (int off = 32; off > 0; off >>= 1) v += __shfl_down(v, off);
    acc[e] = v;
  }
  if (lane == 0) {
    float mx = acc[0];
#pragma unroll
    for (int e = 1; e < NE; ++e) mx = fmaxf(mx, acc[e]);
    float p[NE];
    float sum = 0.f;
#pragma unroll
    for (int e = 0; e < NE; ++e) { p[e] = __expf(acc[e] - mx); sum += p[e]; }
    float inv = 1.f / sum;
    int e0 = 0; float b0 = p[0];
#pragma unroll
    for (int e = 1; e < NE; ++e) if (p[e] > b0) { b0 = p[e]; e0 = e; }
    int e1 = -1; float b1v = -1.f;
#pragma unroll
    for (int e = 0; e < NE; ++e) if (e != e0 && p[e] > b1v) { b1v = p[e]; e1 = e; }
    re[t] = make_int2(e0, e1);
    rs[t] = make_float2(b0 * inv, b1v * inv);
    atomicAdd(&counts[e0], 1);
    atomicAdd(&counts[e1], 1);
  }
}

// ---------------- plan: per-expert offsets + m-block table ----------------
__global__ void k_plan(const int* __restrict__ counts, int* __restrict__ offsets,
                       int* __restrict__ cursors, int* __restrict__ nmb,
                       int* __restrict__ bexp, int* __restrict__ brow0,
                       int* __restrict__ brows) {
  if (threadIdx.x == 0 && blockIdx.x == 0) {
    int off = 0, mb = 0;
    for (int e = 0; e < NE; ++e) {
      offsets[e] = off;
      cursors[e] = off;
      int c = counts[e];
      int nb = (c + 127) >> 7;
      for (int b = 0; b < nb; ++b) {
        bexp[mb] = e;
        brow0[mb] = off + b * 128;
        int r = c - b * 128;
        brows[mb] = r < 128 ? r : 128;
        ++mb;
      }
      off += c;
    }
    *nmb = mb;
  }
}

// ---------------- scatter pairs into expert-sorted order ----------------
// ppos aliases rs (dead after this kernel); s loaded before any ppos store.
__global__ void k_scatter(const int2* __restrict__ re, float2* rs,
                          int* __restrict__ cursors, int* __restrict__ ptok,
                          float* __restrict__ pw, int* ppos) {
  int t = blockIdx.x * 256 + threadIdx.x;
  if (t >= T_TOK) return;
  int2 e = re[t];
  float2 s = rs[t];
  int p0 = atomicAdd(&cursors[e.x], 1);
  ptok[p0] = t; pw[p0] = s.x;
  int p1 = atomicAdd(&cursors[e.y], 1);
  ptok[p1] = t; pw[p1] = s.y;
  ppos[2 * t] = p0;
  ppos[2 * t + 1] = p1;
}

// ---------------- gather tokens into A (f16) ----------------
__global__ void k_gather(const float* __restrict__ x, const int* __restrict__ ptok,
                         _Float16* __restrict__ A) {
  int lane = threadIdx.x & 63;
  int p = blockIdx.x * 4 + (threadIdx.x >> 6);
  int t = ptok[p];
  const float4* src = (const float4*)(x + (size_t)t * HID);
  h4* dst = (h4*)(A + (size_t)p * HID);
#pragma unroll
  for (int i = 0; i < 4; ++i) {
    float4 v = src[lane + 64 * i];
    h4 h;
    h[0] = (_Float16)v.x; h[1] = (_Float16)v.y;
    h[2] = (_Float16)v.z; h[3] = (_Float16)v.w;
    dst[lane + 64 * i] = h;
  }
}

// ---------------- elementwise f32 -> f16 cast ----------------
__global__ void k_cast(const float* __restrict__ src, _Float16* __restrict__ dst, int n4) {
  int i = blockIdx.x * blockDim.x + threadIdx.x;
  int stride = gridDim.x * blockDim.x;
  const float4* s = (const float4*)src;
  h4* d = (h4*)dst;
  for (; i < n4; i += stride) {
    float4 v = s[i];
    h4 h;
    h[0] = (_Float16)v.x; h[1] = (_Float16)v.y;
    h[2] = (_Float16)v.z; h[3] = (_Float16)v.w;
    d[i] = h;
  }
}

// BK=64 LDS chunk swizzle: row stride 64 f16 = 128 B = all 32 banks.
// 8 chunks of 16 B per row; logical chunk q of row r stored at physical
// position (q + r) & 7  ->  on ds_read_b128 fragment reads (16 rows x 4 lq)
// every bank quad is hit by exactly 8 lanes (the b128 optimum).
// Staging pre-swizzles the GLOBAL source address (global_load_lds requires a
// linear lane->LDS mapping): phys slot p of row r holds global chunk (p-r)&7.

// ===================================================================
// fc1: A[pairs,HID] @ W1[e]^T + b1 -> silu -> hmid (f16)
// 128x128 tile, BK=64, double-buffered LDS, 2-phase pipeline:
// issue next tile's global_load_lds BEFORE computing current tile,
// single __syncthreads (vmcnt(0)+lgkmcnt(0)+barrier) per K-tile.
// LDS-staged coalesced epilogue (fixes f16 partial-sector write amp).
// ===================================================================
__global__ __launch_bounds__(256) void k_fc1(
    const _Float16* __restrict__ A, const _Float16* __restrict__ W1h,
    const float* __restrict__ b1, _Float16* __restrict__ hmid,
    const int* __restrict__ nmb, const int* __restrict__ bexp,
    const int* __restrict__ brow0, const int* __restrict__ brows) {
  int mb = blockIdx.y;
  if (mb >= *nmb) return;
  int e = bexp[mb];
  int row0 = brow0[mb];
  int rows = brows[mb];
  int n0 = blockIdx.x * 128;

  // 64 KB: As[2] at 0/8192, Bs[2] at 16384/24576 (f16 units)
  __shared__ _Float16 smem[32768];

  int tid = threadIdx.x;
  int lane = tid & 63;
  int wave = tid >> 6;
  int wr = (wave >> 1) * 64;
  int wc = (wave & 1) * 64;
  int lrow = lane & 15;
  int lq = lane >> 4;

  const _Float16* Ab = A + (size_t)row0 * HID;
  const _Float16* Wb = W1h + (size_t)e * FFN_D * HID + (size_t)n0 * HID;

  v4f acc[4][4];
  v4f z = {0.f, 0.f, 0.f, 0.f};
#pragma unroll
  for (int i = 0; i < 4; ++i)
#pragma unroll
    for (int j = 0; j < 4; ++j) acc[i][j] = z;

  auto stage = [&](int buf, int kt) {
    int k0 = kt * 64;
    _Float16* as = &smem[buf * 8192];
    _Float16* bs = &smem[16384 + buf * 8192];
#pragma unroll
    for (int l = 0; l < 4; ++l) {
      int c = l * 256 + tid;
      int row = c >> 3, pos = c & 7;
      async16(Ab + (size_t)row * HID + k0 + (((pos - row) & 7) << 3), as + c * 8);
    }
#pragma unroll
    for (int l = 0; l < 4; ++l) {
      int c = l * 256 + tid;
      int row = c >> 3, pos = c & 7;
      async16(Wb + (size_t)row * HID + k0 + (((pos - row) & 7) << 3), bs + c * 8);
    }
  };

  const int NT = HID / 64;  // 16
  stage(0, 0);
  __syncthreads();  // tile 0 resident
  for (int t = 0; t < NT; ++t) {
    if (t + 1 < NT) stage((t + 1) & 1, t + 1);  // issue-early: flies during compute
    const _Float16* as = &smem[(t & 1) * 8192];
    const _Float16* bs = &smem[16384 + (t & 1) * 8192];
#pragma unroll
    for (int kk = 0; kk < 2; ++kk) {
      h8 af[4], bf[4];
#pragma unroll
      for (int i = 0; i < 4; ++i) {
        int row = wr + i * 16 + lrow;
        af[i] = *(const h8*)&as[row * 64 + (((kk * 4 + lq + row) & 7) << 3)];
      }
#pragma unroll
      for (int j = 0; j < 4; ++j) {
        int row = wc + j * 16 + lrow;
        bf[j] = *(const h8*)&bs[row * 64 + (((kk * 4 + lq + row) & 7) << 3)];
      }
#pragma unroll
      for (int i = 0; i < 4; ++i)
#pragma unroll
        for (int j = 0; j < 4; ++j)
          acc[i][j] = __builtin_amdgcn_mfma_f32_16x16x32_f16(af[i], bf[j], acc[i][j], 0, 0, 0);
    }
    __syncthreads();  // drains vmcnt(0)+lgkmcnt(0): next tile landed, reads done
  }

  // ---- epilogue: bias+silu -> LDS [128][136] f16 -> coalesced h8 stores ----
  _Float16* ct = smem;  // 128*136 = 17408 f16 = 34816 B < 64 KB
#pragma unroll
  for (int j = 0; j < 4; ++j) {
    float bias = b1[e * FFN_D + n0 + wc + j * 16 + lrow];
#pragma unroll
    for (int i = 0; i < 4; ++i) {
#pragma unroll
      for (int r = 0; r < 4; ++r) {
        float v = acc[i][j][r] + bias;
        float sv = v / (1.f + __expf(-v));
        ct[(wr + i * 16 + lq * 4 + r) * 136 + wc + j * 16 + lrow] = (_Float16)sv;
      }
    }
  }
  __syncthreads();
  int sub = lane >> 4, lr16 = lane & 15;
#pragma unroll
  for (int rr = 0; rr < 8; ++rr) {
    int row = wave * 32 + sub * 8 + rr;
    if (row < rows) {
      h8 v = *(const h8*)&ct[row * 136 + lr16 * 8];
      *(h8*)&hmid[(size_t)(row0 + row) * FFN_D + n0 + lr16 * 8] = v;
    }
  }
}

// ===================================================================
// fc2: hmid @ W2[e]^T + b2, weighted plain store to pairout (f32)
// same 2-phase pipelined main loop, NT = 64.
// ===================================================================
__global__ __launch_bounds__(256) void k_fc2(
    const _Float16* __restrict__ hmid, const _Float16* __restrict__ W2h,
    const float* __restrict__ b2, const float* __restrict__ pw,
    float* __restrict__ pairout,
    const int* __restrict__ nmb, const int* __restrict__ bexp,
    const int* __restrict__ brow0, const int* __restrict__ brows) {
  int mb = blockIdx.y;
  if (mb >= *nmb) return;
  int e = bexp[mb];
  int row0 = brow0[mb];
  int rows = brows[mb];
  int n0 = blockIdx.x * 128;

  __shared__ _Float16 smem[32768];

  int tid = threadIdx.x;
  int lane = tid & 63;
  int wave = tid >> 6;
  int wr = (wave >> 1) * 64;
  int wc = (wave & 1) * 64;
  int lrow = lane & 15;
  int lq = lane >> 4;

  const _Float16* Ab = hmid + (size_t)row0 * FFN_D;
  const _Float16* Wb = W2h + (size_t)e * HID * FFN_D + (size_t)n0 * FFN_D;

  v4f acc[4][4];
  v4f z = {0.f, 0.f, 0.f, 0.f};
#pragma unroll
  for (int i = 0; i < 4; ++i)
#pragma unroll
    for (int j = 0; j < 4; ++j) acc[i][j] = z;

  auto stage = [&](int buf, int kt) {
    int k0 = kt * 64;
    _Float16* as = &smem[buf * 8192];
    _Float16* bs = &smem[16384 + buf * 8192];
#pragma unroll
    for (int l = 0; l < 4; ++l) {
      int c = l * 256 + tid;
      int row = c >> 3, pos = c & 7;
      async16(Ab + (size_t)row * FFN_D + k0 + (((pos - row) & 7) << 3), as + c * 8);
    }
#pragma unroll
    for (int l = 0; l < 4; ++l) {
      int c = l * 256 + tid;
      int row = c >> 3, pos = c & 7;
      async16(Wb + (size_t)row * FFN_D + k0 + (((pos - row) & 7) << 3), bs + c * 8);
    }
  };

  const int NT = FFN_D / 64;  // 64
  stage(0, 0);
  __syncthreads();
  for (int t = 0; t < NT; ++t) {
    if (t + 1 < NT) stage((t + 1) & 1, t + 1);
    const _Float16* as = &smem[(t & 1) * 8192];
    const _Float16* bs = &smem[16384 + (t & 1) * 8192];
#pragma unroll
    for (int kk = 0; kk < 2; ++kk) {
      h8 af[4], bf[4];
#pragma unroll
      for (int i = 0; i < 4; ++i) {
        int row = wr + i * 16 + lrow;
        af[i] = *(const h8*)&as[row * 64 + (((kk * 4 + lq + row) & 7) << 3)];
      }
#pragma unroll
      for (int j = 0; j < 4; ++j) {
        int row = wc + j * 16 + lrow;
        bf[j] = *(const h8*)&bs[row * 64 + (((kk * 4 + lq + row) & 7) << 3)];
      }
#pragma unroll
      for (int i = 0; i < 4; ++i)
#pragma unroll
        for (int j = 0; j < 4; ++j)
          acc[i][j] = __builtin_amdgcn_mfma_f32_16x16x32_f16(af[i], bf[j], acc[i][j], 0, 0, 0);
    }
    __syncthreads();
  }

#pragma unroll
  for (int j = 0; j < 4; ++j) {
    int gcol = n0 + wc + j * 16 + lrow;
    float bias = b2[e * HID + gcol];
#pragma unroll
    for (int i = 0; i < 4; ++i) {
#pragma unroll
      for (int r = 0; r < 4; ++r) {
        int grow = wr + i * 16 + lq * 4 + r;
        if (grow < rows) {
          int row = row0 + grow;
          float w = pw[row];
          pairout[(size_t)row * HID + gcol] = w * (acc[i][j][r] + bias);
        }
      }
    }
  }
}

// ---------------- combine: out[t] = pairout[p0(t)] + pairout[p1(t)] ----------------
__global__ void k_combine(const float* __restrict__ pairout, const int* __restrict__ ppos,
                          float* __restrict__ out) {
  int t = blockIdx.x;
  int c = threadIdx.x;
  int p0 = ppos[2 * t];
  int p1 = ppos[2 * t + 1];
  const float4* a = (const float4*)(pairout + (size_t)p0 * HID);
  const float4* b = (const float4*)(pairout + (size_t)p1 * HID);
  float4 va = a[c];
  float4 vb = b[c];
  float4 o;
  o.x = va.x + vb.x; o.y = va.y + vb.y; o.z = va.z + vb.z; o.w = va.w + vb.w;
  ((float4*)(out + (size_t)t * HID))[c] = o;
}

extern "C" void kernel_launch(void* const* d_in, const int* in_sizes, int n_in,
                              void* d_out, int out_size, void* d_ws, size_t ws_size,
                              hipStream_t stream) {
  const float* x  = (const float*)d_in[0];
  const float* Wr = (const float*)d_in[1];
  const float* W1 = (const float*)d_in[2];
  const float* b1 = (const float*)d_in[3];
  const float* W2 = (const float*)d_in[4];
  const float* b2 = (const float*)d_in[5];
  float* out = (float*)d_out;

  uint8_t* ws = (uint8_t*)d_ws;
  int* meta    = (int*)ws;
  int* counts  = meta;        // 8
  int* cursors = meta + 8;    // 8
  int* offsets = meta + 16;   // 8
  int* nmb     = meta + 24;   // 1
  int* bexp    = meta + 32;   // 160
  int* brow0   = meta + 192;  // 160
  int* brows   = meta + 352;  // 160
  int2*   re   = (int2*)(ws + 4096);
  float2* rs   = (float2*)(ws + 69632);
  int*    ppos = (int*)(ws + 69632);             // aliases rs (dead after k_scatter)
  int*    ptok = (int*)(ws + 135168);
  float*  pw   = (float*)(ws + 201216);
  _Float16* A    = (_Float16*)(ws + 267264);     // [16512,1024]
  _Float16* W1h  = (_Float16*)(ws + 34083840);   // [8,4096,1024]
  float* pairout = (float*)(ws + 34083840);      // [16384,1024] f32, aliases W1h (dead after fc1)
  _Float16* W2h  = (_Float16*)(ws + 101192704);  // [8,1024,4096]
  _Float16* hmid = (_Float16*)(ws + 168301568);  // [16512,4096]

  hipMemsetAsync(ws, 0, 4096, stream);

  k_router<<<T_TOK / 4, 256, 0, stream>>>(x, Wr, re, rs, counts);
  k_plan<<<1, 64, 0, stream>>>(counts, offsets, cursors, nmb, bexp, brow0, brows);
  k_scatter<<<T_TOK / 256, 256, 0, stream>>>(re, rs, cursors, ptok, pw, ppos);
  k_gather<<<NPAIR / 4, 256, 0, stream>>>(x, ptok, A);
  k_cast<<<2048, 256, 0, stream>>>(W1, W1h, NE * FFN_D * HID / 4);
  k_cast<<<2048, 256, 0, stream>>>(W2, W2h, NE * HID * FFN_D / 4);
  k_fc1<<<dim3(FFN_D / 128, MAXMB), 256, 0, stream>>>(A, W1h, b1, hmid, nmb, bexp, brow0, brows);
  k_fc2<<<dim3(HID / 128, MAXMB), 256, 0, stream>>>(hmid, W2h, b2, pw, pairout, nmb, bexp, brow0, brows);
  k_combine<<<T_TOK, 256, 0, stream>>>(pairout, ppos, out);
}

// Round 4
// 1017.976 us; speedup vs baseline: 1.1393x; 1.0519x over previous
//
#include <hip/hip_runtime.h>
#include <hip/hip_bf16.h>
#include <stdint.h>

#define T_TOK 8192
#define HID 1024
#define FFN_D 4096
#define NE 8
#define NPAIR 16384
#define NPAIR_PAD 16512
#define MAXMB 136

typedef _Float16 h8 __attribute__((ext_vector_type(8)));
typedef _Float16 h4 __attribute__((ext_vector_type(4)));
typedef float v4f __attribute__((ext_vector_type(4)));

__device__ __forceinline__ void async16(const void* g, void* l) {
  auto gp = (const __attribute__((address_space(1))) uint32_t*)(uintptr_t)g;
  auto lp = (__attribute__((address_space(3))) uint32_t*)(uintptr_t)l;
  __builtin_amdgcn_global_load_lds(gp, lp, 16, 0, 0);
}

#define SBAR() __builtin_amdgcn_sched_barrier(0)
#define RBAR() __builtin_amdgcn_s_barrier()

// ---------------- router: logits -> softmax -> top2 ----------------
__global__ void k_router(const float* __restrict__ x, const float* __restrict__ Wr,
                         int2* __restrict__ re, float2* __restrict__ rs,
                         int* __restrict__ counts) {
  int lane = threadIdx.x & 63;
  int t = blockIdx.x * 4 + (threadIdx.x >> 6);
  const float* xt = x + (size_t)t * HID;
  float acc[NE];
#pragma unroll
  for (int e = 0; e < NE; ++e) acc[e] = 0.f;
  for (int i = 0; i < HID / 64; ++i) {
    float xv = xt[lane + 64 * i];
#pragma unroll
    for (int e = 0; e < NE; ++e) acc[e] += xv * Wr[e * HID + lane + 64 * i];
  }
#pragma unroll
  for (int e = 0; e < NE; ++e) {
    float v = acc[e];
#pragma unroll
    for (int off = 32; off > 0; off >>= 1) v += __shfl_down(v, off);
    acc[e] = v;
  }
  if (lane == 0) {
    float mx = acc[0];
#pragma unroll
    for (int e = 1; e < NE; ++e) mx = fmaxf(mx, acc[e]);
    float p[NE];
    float sum = 0.f;
#pragma unroll
    for (int e = 0; e < NE; ++e) { p[e] = __expf(acc[e] - mx); sum += p[e]; }
    float inv = 1.f / sum;
    int e0 = 0; float b0 = p[0];
#pragma unroll
    for (int e = 1; e < NE; ++e) if (p[e] > b0) { b0 = p[e]; e0 = e; }
    int e1 = -1; float b1v = -1.f;
#pragma unroll
    for (int e = 0; e < NE; ++e) if (e != e0 && p[e] > b1v) { b1v = p[e]; e1 = e; }
    re[t] = make_int2(e0, e1);
    rs[t] = make_float2(b0 * inv, b1v * inv);
    atomicAdd(&counts[e0], 1);
    atomicAdd(&counts[e1], 1);
  }
}

// ---------------- plan: per-expert offsets + m-block table ----------------
__global__ void k_plan(const int* __restrict__ counts, int* __restrict__ offsets,
                       int* __restrict__ cursors, int* __restrict__ nmb,
                       int* __restrict__ bexp, int* __restrict__ brow0,
                       int* __restrict__ brows) {
  if (threadIdx.x == 0 && blockIdx.x == 0) {
    int off = 0, mb = 0;
    for (int e = 0; e < NE; ++e) {
      offsets[e] = off;
      cursors[e] = off;
      int c = counts[e];
      int nb = (c + 127) >> 7;
      for (int b = 0; b < nb; ++b) {
        bexp[mb] = e;
        brow0[mb] = off + b * 128;
        int r = c - b * 128;
        brows[mb] = r < 128 ? r : 128;
        ++mb;
      }
      off += c;
    }
    *nmb = mb;
  }
}

// ---------------- scatter pairs into expert-sorted order ----------------
// ppos aliases rs (dead after this kernel); s loaded before any ppos store.
__global__ void k_scatter(const int2* __restrict__ re, float2* rs,
                          int* __restrict__ cursors, int* __restrict__ ptok,
                          float* __restrict__ pw, int* ppos) {
  int t = blockIdx.x * 256 + threadIdx.x;
  if (t >= T_TOK) return;
  int2 e = re[t];
  float2 s = rs[t];
  int p0 = atomicAdd(&cursors[e.x], 1);
  ptok[p0] = t; pw[p0] = s.x;
  int p1 = atomicAdd(&cursors[e.y], 1);
  ptok[p1] = t; pw[p1] = s.y;
  ppos[2 * t] = p0;
  ppos[2 * t + 1] = p1;
}

// ---------------- gather tokens into A (f16) ----------------
__global__ void k_gather(const float* __restrict__ x, const int* __restrict__ ptok,
                         _Float16* __restrict__ A) {
  int lane = threadIdx.x & 63;
  int p = blockIdx.x * 4 + (threadIdx.x >> 6);
  int t = ptok[p];
  const float4* src = (const float4*)(x + (size_t)t * HID);
  h4* dst = (h4*)(A + (size_t)p * HID);
#pragma unroll
  for (int i = 0; i < 4; ++i) {
    float4 v = src[lane + 64 * i];
    h4 h;
    h[0] = (_Float16)v.x; h[1] = (_Float16)v.y;
    h[2] = (_Float16)v.z; h[3] = (_Float16)v.w;
    dst[lane + 64 * i] = h;
  }
}

// ---------------- elementwise f32 -> f16 cast ----------------
__global__ void k_cast(const float* __restrict__ src, _Float16* __restrict__ dst, int n4) {
  int i = blockIdx.x * blockDim.x + threadIdx.x;
  int stride = gridDim.x * blockDim.x;
  const float4* s = (const float4*)src;
  h4* d = (h4*)dst;
  for (; i < n4; i += stride) {
    float4 v = s[i];
    h4 h;
    h[0] = (_Float16)v.x; h[1] = (_Float16)v.y;
    h[2] = (_Float16)v.z; h[3] = (_Float16)v.w;
    d[i] = h;
  }
}

// BK=32 LDS chunk-position swizzle (verified round 0): logical k-chunk c of
// row r stored at position (c + (r>>1)) & 3. Conflict-free ds_read_b128.
// Staging pre-swizzles the GLOBAL source address (global_load_lds needs a
// linear lane->LDS mapping).
#define SWZ_POS(r, c) (((c) + ((r) >> 1)) & 3)
#define SWZ_CHUNK(r, p) (((p) - ((r) >> 1)) & 3)

// ===================================================================
// fc1: A[pairs,HID] @ W1[e]^T + b1 -> silu -> hmid (f16)
// 128x128 tile, BK=32, TRIPLE-buffered LDS (48 KB -> 3 blocks/CU),
// prefetch depth 2, counted vmcnt(8) (never 0 mid-loop), raw barriers.
// XCD-chunked block swizzle for L2 locality.
// ===================================================================
__global__ __launch_bounds__(256, 3) void k_fc1(
    const _Float16* __restrict__ A, const _Float16* __restrict__ W1h,
    const float* __restrict__ b1, _Float16* __restrict__ hmid,
    const int* __restrict__ nmb, const int* __restrict__ bexp,
    const int* __restrict__ brow0, const int* __restrict__ brows) {
  // XCD swizzle: nx=32 n-blocks. total = 136*32 (div by 8) -> bijective.
  int lid = blockIdx.y * 32 + blockIdx.x;
  int nlid = (lid & 7) * (MAXMB * 32 / 8) + (lid >> 3);
  int mb = nlid >> 5;
  int n0 = (nlid & 31) * 128;
  if (mb >= *nmb) return;
  int e = bexp[mb];
  int row0 = brow0[mb];
  int rows = brows[mb];

  // 3 buffers x (As 4096 + Bs 4096) f16 = 48 KB
  __shared__ _Float16 smem[24576];

  int tid = threadIdx.x;
  int lane = tid & 63;
  int wave = tid >> 6;
  int wr = (wave >> 1) * 64;
  int wc = (wave & 1) * 64;
  int lrow = lane & 15;
  int lq = lane >> 4;

  const _Float16* Ab = A + (size_t)row0 * HID;
  const _Float16* Wb = W1h + (size_t)e * FFN_D * HID + (size_t)n0 * HID;

  v4f acc[4][4];
  v4f z = {0.f, 0.f, 0.f, 0.f};
#pragma unroll
  for (int i = 0; i < 4; ++i)
#pragma unroll
    for (int j = 0; j < 4; ++j) acc[i][j] = z;

  auto stage = [&](int buf, int kt) {  // 4 loads/thread
    int k0 = kt * 32;
    _Float16* as = &smem[buf * 8192];
    _Float16* bs = as + 4096;
#pragma unroll
    for (int l = 0; l < 2; ++l) {
      int c = l * 256 + tid;
      int row = c >> 2, pos = c & 3;
      async16(Ab + (size_t)row * HID + k0 + SWZ_CHUNK(row, pos) * 8, as + c * 8);
    }
#pragma unroll
    for (int l = 0; l < 2; ++l) {
      int c = l * 256 + tid;
      int row = c >> 2, pos = c & 3;
      async16(Wb + (size_t)row * HID + k0 + SWZ_CHUNK(row, pos) * 8, bs + c * 8);
    }
  };

  const int NT = HID / 32;  // 32
  stage(0, 0);
  stage(1, 1);
  for (int t = 0; t < NT; ++t) {
    if (t + 2 < NT) stage((t + 2) % 3, t + 2);  // depth-2 prefetch
    SBAR();
    if (t + 2 < NT)      asm volatile("s_waitcnt vmcnt(8)" ::: "memory");
    else if (t + 1 < NT) asm volatile("s_waitcnt vmcnt(4)" ::: "memory");
    else                 asm volatile("s_waitcnt vmcnt(0)" ::: "memory");
    RBAR();  // tile t resident for all waves
    SBAR();
    const _Float16* as = &smem[(t % 3) * 8192];
    const _Float16* bs = as + 4096;
    h8 af[4], bf[4];
#pragma unroll
    for (int i = 0; i < 4; ++i) {
      int row = wr + i * 16 + lrow;
      af[i] = *(const h8*)&as[row * 32 + SWZ_POS(row, lq) * 8];
    }
#pragma unroll
    for (int j = 0; j < 4; ++j) {
      int row = wc + j * 16 + lrow;
      bf[j] = *(const h8*)&bs[row * 32 + SWZ_POS(row, lq) * 8];
    }
#pragma unroll
    for (int i = 0; i < 4; ++i)
#pragma unroll
      for (int j = 0; j < 4; ++j)
        acc[i][j] = __builtin_amdgcn_mfma_f32_16x16x32_f16(af[i], bf[j], acc[i][j], 0, 0, 0);
    SBAR();
    RBAR();  // all waves done reading buf t%3 before iter t+1 overwrites it
  }

  // ---- epilogue: bias+silu -> LDS [128][136] f16 -> coalesced h8 stores ----
  _Float16* ct = smem;  // 128*136 = 17408 f16 = 34816 B < 48 KB
#pragma unroll
  for (int j = 0; j < 4; ++j) {
    float bias = b1[e * FFN_D + n0 + wc + j * 16 + lrow];
#pragma unroll
    for (int i = 0; i < 4; ++i) {
#pragma unroll
      for (int r = 0; r < 4; ++r) {
        float v = acc[i][j][r] + bias;
        float sv = v / (1.f + __expf(-v));
        ct[(wr + i * 16 + lq * 4 + r) * 136 + wc + j * 16 + lrow] = (_Float16)sv;
      }
    }
  }
  __syncthreads();
  int sub = lane >> 4, lr16 = lane & 15;
#pragma unroll
  for (int rr = 0; rr < 8; ++rr) {
    int row = wave * 32 + sub * 8 + rr;
    if (row < rows) {
      h8 v = *(const h8*)&ct[row * 136 + lr16 * 8];
      *(h8*)&hmid[(size_t)(row0 + row) * FFN_D + n0 + lr16 * 8] = v;
    }
  }
}

// ===================================================================
// fc2: hmid @ W2[e]^T + b2, weighted plain store to pairout (f32)
// same triple-buffered counted-vmcnt main loop, NT = 128.
// ===================================================================
__global__ __launch_bounds__(256, 3) void k_fc2(
    const _Float16* __restrict__ hmid, const _Float16* __restrict__ W2h,
    const float* __restrict__ b2, const float* __restrict__ pw,
    float* __restrict__ pairout,
    const int* __restrict__ nmb, const int* __restrict__ bexp,
    const int* __restrict__ brow0, const int* __restrict__ brows) {
  // XCD swizzle: nx=8 n-blocks. total = 136*8 (div by 8) -> bijective.
  int lid = blockIdx.y * 8 + blockIdx.x;
  int nlid = (lid & 7) * (MAXMB * 8 / 8) + (lid >> 3);
  int mb = nlid >> 3;
  int n0 = (nlid & 7) * 128;
  if (mb >= *nmb) return;
  int e = bexp[mb];
  int row0 = brow0[mb];
  int rows = brows[mb];

  __shared__ _Float16 smem[24576];

  int tid = threadIdx.x;
  int lane = tid & 63;
  int wave = tid >> 6;
  int wr = (wave >> 1) * 64;
  int wc = (wave & 1) * 64;
  int lrow = lane & 15;
  int lq = lane >> 4;

  const _Float16* Ab = hmid + (size_t)row0 * FFN_D;
  const _Float16* Wb = W2h + (size_t)e * HID * FFN_D + (size_t)n0 * FFN_D;

  v4f acc[4][4];
  v4f z = {0.f, 0.f, 0.f, 0.f};
#pragma unroll
  for (int i = 0; i < 4; ++i)
#pragma unroll
    for (int j = 0; j < 4; ++j) acc[i][j] = z;

  auto stage = [&](int buf, int kt) {  // 4 loads/thread
    int k0 = kt * 32;
    _Float16* as = &smem[buf * 8192];
    _Float16* bs = as + 4096;
#pragma unroll
    for (int l = 0; l < 2; ++l) {
      int c = l * 256 + tid;
      int row = c >> 2, pos = c & 3;
      async16(Ab + (size_t)row * FFN_D + k0 + SWZ_CHUNK(row, pos) * 8, as + c * 8);
    }
#pragma unroll
    for (int l = 0; l < 2; ++l) {
      int c = l * 256 + tid;
      int row = c >> 2, pos = c & 3;
      async16(Wb + (size_t)row * FFN_D + k0 + SWZ_CHUNK(row, pos) * 8, bs + c * 8);
    }
  };

  const int NT = FFN_D / 32;  // 128
  stage(0, 0);
  stage(1, 1);
  for (int t = 0; t < NT; ++t) {
    if (t + 2 < NT) stage((t + 2) % 3, t + 2);
    SBAR();
    if (t + 2 < NT)      asm volatile("s_waitcnt vmcnt(8)" ::: "memory");
    else if (t + 1 < NT) asm volatile("s_waitcnt vmcnt(4)" ::: "memory");
    else                 asm volatile("s_waitcnt vmcnt(0)" ::: "memory");
    RBAR();
    SBAR();
    const _Float16* as = &smem[(t % 3) * 8192];
    const _Float16* bs = as + 4096;
    h8 af[4], bf[4];
#pragma unroll
    for (int i = 0; i < 4; ++i) {
      int row = wr + i * 16 + lrow;
      af[i] = *(const h8*)&as[row * 32 + SWZ_POS(row, lq) * 8];
    }
#pragma unroll
    for (int j = 0; j < 4; ++j) {
      int row = wc + j * 16 + lrow;
      bf[j] = *(const h8*)&bs[row * 32 + SWZ_POS(row, lq) * 8];
    }
#pragma unroll
    for (int i = 0; i < 4; ++i)
#pragma unroll
      for (int j = 0; j < 4; ++j)
        acc[i][j] = __builtin_amdgcn_mfma_f32_16x16x32_f16(af[i], bf[j], acc[i][j], 0, 0, 0);
    SBAR();
    RBAR();
  }

#pragma unroll
  for (int j = 0; j < 4; ++j) {
    int gcol = n0 + wc + j * 16 + lrow;
    float bias = b2[e * HID + gcol];
#pragma unroll
    for (int i = 0; i < 4; ++i) {
#pragma unroll
      for (int r = 0; r < 4; ++r) {
        int grow = wr + i * 16 + lq * 4 + r;
        if (grow < rows) {
          int row = row0 + grow;
          float w = pw[row];
          pairout[(size_t)row * HID + gcol] = w * (acc[i][j][r] + bias);
        }
      }
    }
  }
}

// ---------------- combine: out[t] = pairout[p0(t)] + pairout[p1(t)] ----------------
__global__ void k_combine(const float* __restrict__ pairout, const int* __restrict__ ppos,
                          float* __restrict__ out) {
  int t = blockIdx.x;
  int c = threadIdx.x;
  int p0 = ppos[2 * t];
  int p1 = ppos[2 * t + 1];
  const float4* a = (const float4*)(pairout + (size_t)p0 * HID);
  const float4* b = (const float4*)(pairout + (size_t)p1 * HID);
  float4 va = a[c];
  float4 vb = b[c];
  float4 o;
  o.x = va.x + vb.x; o.y = va.y + vb.y; o.z = va.z + vb.z; o.w = va.w + vb.w;
  ((float4*)(out + (size_t)t * HID))[c] = o;
}

extern "C" void kernel_launch(void* const* d_in, const int* in_sizes, int n_in,
                              void* d_out, int out_size, void* d_ws, size_t ws_size,
                              hipStream_t stream) {
  const float* x  = (const float*)d_in[0];
  const float* Wr = (const float*)d_in[1];
  const float* W1 = (const float*)d_in[2];
  const float* b1 = (const float*)d_in[3];
  const float* W2 = (const float*)d_in[4];
  const float* b2 = (const float*)d_in[5];
  float* out = (float*)d_out;

  uint8_t* ws = (uint8_t*)d_ws;
  int* meta    = (int*)ws;
  int* counts  = meta;        // 8
  int* cursors = meta + 8;    // 8
  int* offsets = meta + 16;   // 8
  int* nmb     = meta + 24;   // 1
  int* bexp    = meta + 32;   // 160
  int* brow0   = meta + 192;  // 160
  int* brows   = meta + 352;  // 160
  int2*   re   = (int2*)(ws + 4096);
  float2* rs   = (float2*)(ws + 69632);
  int*    ppos = (int*)(ws + 69632);             // aliases rs (dead after k_scatter)
  int*    ptok = (int*)(ws + 135168);
  float*  pw   = (float*)(ws + 201216);
  _Float16* A    = (_Float16*)(ws + 267264);     // [16512,1024]
  _Float16* W1h  = (_Float16*)(ws + 34083840);   // [8,4096,1024]
  float* pairout = (float*)(ws + 34083840);      // [16384,1024] f32, aliases W1h (dead after fc1)
  _Float16* W2h  = (_Float16*)(ws + 101192704);  // [8,1024,4096]
  _Float16* hmid = (_Float16*)(ws + 168301568);  // [16512,4096]

  hipMemsetAsync(ws, 0, 4096, stream);

  k_router<<<T_TOK / 4, 256, 0, stream>>>(x, Wr, re, rs, counts);
  k_plan<<<1, 64, 0, stream>>>(counts, offsets, cursors, nmb, bexp, brow0, brows);
  k_scatter<<<T_TOK / 256, 256, 0, stream>>>(re, rs, cursors, ptok, pw, ppos);
  k_gather<<<NPAIR / 4, 256, 0, stream>>>(x, ptok, A);
  k_cast<<<2048, 256, 0, stream>>>(W1, W1h, NE * FFN_D * HID / 4);
  k_cast<<<2048, 256, 0, stream>>>(W2, W2h, NE * HID * FFN_D / 4);
  k_fc1<<<dim3(FFN_D / 128, MAXMB), 256, 0, stream>>>(A, W1h, b1, hmid, nmb, bexp, brow0, brows);
  k_fc2<<<dim3(HID / 128, MAXMB), 256, 0, stream>>>(hmid, W2h, b2, pw, pairout, nmb, bexp, brow0, brows);
  k_combine<<<T_TOK, 256, 0, stream>>>(pairout, ppos, out);
}

// Round 5
// 1009.902 us; speedup vs baseline: 1.1484x; 1.0080x over previous
//
#include <hip/hip_runtime.h>
#include <hip/hip_bf16.h>
#include <stdint.h>

#define T_TOK 8192
#define HID 1024
#define FFN_D 4096
#define NE 8
#define NPAIR 16384
#define NPAIR_PAD 16512
#define MAXMB 136

typedef _Float16 h8 __attribute__((ext_vector_type(8)));
typedef _Float16 h4 __attribute__((ext_vector_type(4)));
typedef float v4f __attribute__((ext_vector_type(4)));

__device__ __forceinline__ void async16(const void* g, void* l) {
  auto gp = (const __attribute__((address_space(1))) uint32_t*)(uintptr_t)g;
  auto lp = (__attribute__((address_space(3))) uint32_t*)(uintptr_t)l;
  __builtin_amdgcn_global_load_lds(gp, lp, 16, 0, 0);
}

#define SBAR() __builtin_amdgcn_sched_barrier(0)
#define RBAR() __builtin_amdgcn_s_barrier()

// ---------------- router: logits -> softmax -> top2 ----------------
__global__ void k_router(const float* __restrict__ x, const float* __restrict__ Wr,
                         int2* __restrict__ re, float2* __restrict__ rs,
                         int* __restrict__ counts) {
  int lane = threadIdx.x & 63;
  int t = blockIdx.x * 4 + (threadIdx.x >> 6);
  const float* xt = x + (size_t)t * HID;
  float acc[NE];
#pragma unroll
  for (int e = 0; e < NE; ++e) acc[e] = 0.f;
  for (int i = 0; i < HID / 64; ++i) {
    float xv = xt[lane + 64 * i];
#pragma unroll
    for (int e = 0; e < NE; ++e) acc[e] += xv * Wr[e * HID + lane + 64 * i];
  }
#pragma unroll
  for (int e = 0; e < NE; ++e) {
    float v = acc[e];
#pragma unroll
    for (int off = 32; off > 0; off >>= 1) v += __shfl_down(v, off);
    acc[e] = v;
  }
  if (lane == 0) {
    float mx = acc[0];
#pragma unroll
    for (int e = 1; e < NE; ++e) mx = fmaxf(mx, acc[e]);
    float p[NE];
    float sum = 0.f;
#pragma unroll
    for (int e = 0; e < NE; ++e) { p[e] = __expf(acc[e] - mx); sum += p[e]; }
    float inv = 1.f / sum;
    int e0 = 0; float b0 = p[0];
#pragma unroll
    for (int e = 1; e < NE; ++e) if (p[e] > b0) { b0 = p[e]; e0 = e; }
    int e1 = -1; float b1v = -1.f;
#pragma unroll
    for (int e = 0; e < NE; ++e) if (e != e0 && p[e] > b1v) { b1v = p[e]; e1 = e; }
    re[t] = make_int2(e0, e1);
    rs[t] = make_float2(b0 * inv, b1v * inv);
    atomicAdd(&counts[e0], 1);
    atomicAdd(&counts[e1], 1);
  }
}

// ---------------- plan: per-expert offsets + m-block table ----------------
__global__ void k_plan(const int* __restrict__ counts, int* __restrict__ offsets,
                       int* __restrict__ cursors, int* __restrict__ nmb,
                       int* __restrict__ bexp, int* __restrict__ brow0,
                       int* __restrict__ brows) {
  if (threadIdx.x == 0 && blockIdx.x == 0) {
    int off = 0, mb = 0;
    for (int e = 0; e < NE; ++e) {
      offsets[e] = off;
      cursors[e] = off;
      int c = counts[e];
      int nb = (c + 127) >> 7;
      for (int b = 0; b < nb; ++b) {
        bexp[mb] = e;
        brow0[mb] = off + b * 128;
        int r = c - b * 128;
        brows[mb] = r < 128 ? r : 128;
        ++mb;
      }
      off += c;
    }
    *nmb = mb;
  }
}

// ---------------- scatter pairs into expert-sorted order ----------------
// ppos aliases rs (dead after this kernel); s loaded before any ppos store.
__global__ void k_scatter(const int2* __restrict__ re, float2* rs,
                          int* __restrict__ cursors, int* __restrict__ ptok,
                          float* __restrict__ pw, int* ppos) {
  int t = blockIdx.x * 256 + threadIdx.x;
  if (t >= T_TOK) return;
  int2 e = re[t];
  float2 s = rs[t];
  int p0 = atomicAdd(&cursors[e.x], 1);
  ptok[p0] = t; pw[p0] = s.x;
  int p1 = atomicAdd(&cursors[e.y], 1);
  ptok[p1] = t; pw[p1] = s.y;
  ppos[2 * t] = p0;
  ppos[2 * t + 1] = p1;
}

// ---------------- gather tokens into A (f16) ----------------
__global__ void k_gather(const float* __restrict__ x, const int* __restrict__ ptok,
                         _Float16* __restrict__ A) {
  int lane = threadIdx.x & 63;
  int p = blockIdx.x * 4 + (threadIdx.x >> 6);
  int t = ptok[p];
  const float4* src = (const float4*)(x + (size_t)t * HID);
  h4* dst = (h4*)(A + (size_t)p * HID);
#pragma unroll
  for (int i = 0; i < 4; ++i) {
    float4 v = src[lane + 64 * i];
    h4 h;
    h[0] = (_Float16)v.x; h[1] = (_Float16)v.y;
    h[2] = (_Float16)v.z; h[3] = (_Float16)v.w;
    dst[lane + 64 * i] = h;
  }
}

// ---------------- fused f32 -> f16 cast of both weight tensors ----------------
__global__ void k_cast2(const float* __restrict__ s1, _Float16* __restrict__ d1,
                        const float* __restrict__ s2, _Float16* __restrict__ d2,
                        int n4each) {
  int i = blockIdx.x * blockDim.x + threadIdx.x;
  int stride = gridDim.x * blockDim.x;
  for (; i < 2 * n4each; i += stride) {
    const float4* s = (i < n4each) ? (const float4*)s1 : (const float4*)s2;
    h4* d = (i < n4each) ? (h4*)d1 : (h4*)d2;
    int k = (i < n4each) ? i : i - n4each;
    float4 v = s[k];
    h4 h;
    h[0] = (_Float16)v.x; h[1] = (_Float16)v.y;
    h[2] = (_Float16)v.z; h[3] = (_Float16)v.w;
    d[k] = h;
  }
}

// BK=32 LDS chunk-position swizzle (verified round 0): logical k-chunk c of
// row r stored at position (c + (r>>1)) & 3. Conflict-free ds_read_b128.
// Staging pre-swizzles the GLOBAL source address (global_load_lds needs a
// linear lane->LDS mapping).
#define SWZ_POS(r, c) (((c) + ((r) >> 1)) & 3)
#define SWZ_CHUNK(r, p) (((p) - ((r) >> 1)) & 3)

// ===================================================================
// fc1: A[pairs,HID] @ W1[e]^T + b1 -> silu -> hmid (f16)
// 128x128 tile, BK=32, triple-buffered LDS (48 KB, 3 blocks/CU),
// prefetch depth 2, counted vmcnt(4), SINGLE barrier per K-tile:
//   wait vmcnt -> s_barrier -> stage(t+2) -> ds_read(t) -> MFMA.
// WAR-safe: at the barrier every wave has consumed its iter t-1 reads
// (lgkmcnt precedes the MFMAs that precede the barrier), and stage(t+2)
// overwrites buf (t-1)%3 only after it. setprio(1) around MFMA cluster.
// ===================================================================
__global__ __launch_bounds__(256, 3) void k_fc1(
    const _Float16* __restrict__ A, const _Float16* __restrict__ W1h,
    const float* __restrict__ b1, _Float16* __restrict__ hmid,
    const int* __restrict__ nmb, const int* __restrict__ bexp,
    const int* __restrict__ brow0, const int* __restrict__ brows) {
  // XCD swizzle: nx=32 n-blocks. total = 136*32 (div by 8) -> bijective.
  int lid = blockIdx.y * 32 + blockIdx.x;
  int nlid = (lid & 7) * (MAXMB * 32 / 8) + (lid >> 3);
  int mb = nlid >> 5;
  int n0 = (nlid & 31) * 128;
  if (mb >= *nmb) return;
  int e = bexp[mb];
  int row0 = brow0[mb];
  int rows = brows[mb];

  // 3 buffers x (As 4096 + Bs 4096) f16 = 48 KB
  __shared__ _Float16 smem[24576];

  int tid = threadIdx.x;
  int lane = tid & 63;
  int wave = tid >> 6;
  int wr = (wave >> 1) * 64;
  int wc = (wave & 1) * 64;
  int lrow = lane & 15;
  int lq = lane >> 4;

  const _Float16* Ab = A + (size_t)row0 * HID;
  const _Float16* Wb = W1h + (size_t)e * FFN_D * HID + (size_t)n0 * HID;

  v4f acc[4][4];
  v4f z = {0.f, 0.f, 0.f, 0.f};
#pragma unroll
  for (int i = 0; i < 4; ++i)
#pragma unroll
    for (int j = 0; j < 4; ++j) acc[i][j] = z;

  auto stage = [&](int buf, int kt) {  // 4 loads/thread
    int k0 = kt * 32;
    _Float16* as = &smem[buf * 8192];
    _Float16* bs = as + 4096;
#pragma unroll
    for (int l = 0; l < 2; ++l) {
      int c = l * 256 + tid;
      int row = c >> 2, pos = c & 3;
      async16(Ab + (size_t)row * HID + k0 + SWZ_CHUNK(row, pos) * 8, as + c * 8);
    }
#pragma unroll
    for (int l = 0; l < 2; ++l) {
      int c = l * 256 + tid;
      int row = c >> 2, pos = c & 3;
      async16(Wb + (size_t)row * HID + k0 + SWZ_CHUNK(row, pos) * 8, bs + c * 8);
    }
  };

  const int NT = HID / 32;  // 32
  stage(0, 0);
  stage(1, 1);
  for (int t = 0; t < NT; ++t) {
    SBAR();
    if (t + 1 < NT) asm volatile("s_waitcnt vmcnt(4)" ::: "memory");
    else            asm volatile("s_waitcnt vmcnt(0)" ::: "memory");
    RBAR();  // tile t resident; iter t-1 reads consumed chip-wide
    SBAR();
    if (t + 2 < NT) stage((t + 2) % 3, t + 2);  // overwrites buf (t-1)%3: safe
    const _Float16* as = &smem[(t % 3) * 8192];
    const _Float16* bs = as + 4096;
    h8 af[4], bf[4];
#pragma unroll
    for (int i = 0; i < 4; ++i) {
      int row = wr + i * 16 + lrow;
      af[i] = *(const h8*)&as[row * 32 + SWZ_POS(row, lq) * 8];
    }
#pragma unroll
    for (int j = 0; j < 4; ++j) {
      int row = wc + j * 16 + lrow;
      bf[j] = *(const h8*)&bs[row * 32 + SWZ_POS(row, lq) * 8];
    }
    __builtin_amdgcn_s_setprio(1);
#pragma unroll
    for (int i = 0; i < 4; ++i)
#pragma unroll
      for (int j = 0; j < 4; ++j)
        acc[i][j] = __builtin_amdgcn_mfma_f32_16x16x32_f16(af[i], bf[j], acc[i][j], 0, 0, 0);
    __builtin_amdgcn_s_setprio(0);
  }
  __syncthreads();  // all waves out of main loop before smem reuse below

  // ---- epilogue: bias+silu -> LDS [128][136] f16 -> coalesced h8 stores ----
  _Float16* ct = smem;  // 128*136 = 17408 f16 = 34816 B < 48 KB
#pragma unroll
  for (int j = 0; j < 4; ++j) {
    float bias = b1[e * FFN_D + n0 + wc + j * 16 + lrow];
#pragma unroll
    for (int i = 0; i < 4; ++i) {
#pragma unroll
      for (int r = 0; r < 4; ++r) {
        float v = acc[i][j][r] + bias;
        float sv = v / (1.f + __expf(-v));
        ct[(wr + i * 16 + lq * 4 + r) * 136 + wc + j * 16 + lrow] = (_Float16)sv;
      }
    }
  }
  __syncthreads();
  int sub = lane >> 4, lr16 = lane & 15;
#pragma unroll
  for (int rr = 0; rr < 8; ++rr) {
    int row = wave * 32 + sub * 8 + rr;
    if (row < rows) {
      h8 v = *(const h8*)&ct[row * 136 + lr16 * 8];
      *(h8*)&hmid[(size_t)(row0 + row) * FFN_D + n0 + lr16 * 8] = v;
    }
  }
}

// ===================================================================
// fc2: hmid @ W2[e]^T + b2, weighted plain store to pairout (f32)
// same single-barrier counted-vmcnt main loop, NT = 128.
// ===================================================================
__global__ __launch_bounds__(256, 3) void k_fc2(
    const _Float16* __restrict__ hmid, const _Float16* __restrict__ W2h,
    const float* __restrict__ b2, const float* __restrict__ pw,
    float* __restrict__ pairout,
    const int* __restrict__ nmb, const int* __restrict__ bexp,
    const int* __restrict__ brow0, const int* __restrict__ brows) {
  // XCD swizzle: nx=8 n-blocks. total = 136*8 (div by 8) -> bijective.
  int lid = blockIdx.y * 8 + blockIdx.x;
  int nlid = (lid & 7) * (MAXMB * 8 / 8) + (lid >> 3);
  int mb = nlid >> 3;
  int n0 = (nlid & 7) * 128;
  if (mb >= *nmb) return;
  int e = bexp[mb];
  int row0 = brow0[mb];
  int rows = brows[mb];

  __shared__ _Float16 smem[24576];

  int tid = threadIdx.x;
  int lane = tid & 63;
  int wave = tid >> 6;
  int wr = (wave >> 1) * 64;
  int wc = (wave & 1) * 64;
  int lrow = lane & 15;
  int lq = lane >> 4;

  const _Float16* Ab = hmid + (size_t)row0 * FFN_D;
  const _Float16* Wb = W2h + (size_t)e * HID * FFN_D + (size_t)n0 * FFN_D;

  v4f acc[4][4];
  v4f z = {0.f, 0.f, 0.f, 0.f};
#pragma unroll
  for (int i = 0; i < 4; ++i)
#pragma unroll
    for (int j = 0; j < 4; ++j) acc[i][j] = z;

  auto stage = [&](int buf, int kt) {  // 4 loads/thread
    int k0 = kt * 32;
    _Float16* as = &smem[buf * 8192];
    _Float16* bs = as + 4096;
#pragma unroll
    for (int l = 0; l < 2; ++l) {
      int c = l * 256 + tid;
      int row = c >> 2, pos = c & 3;
      async16(Ab + (size_t)row * FFN_D + k0 + SWZ_CHUNK(row, pos) * 8, as + c * 8);
    }
#pragma unroll
    for (int l = 0; l < 2; ++l) {
      int c = l * 256 + tid;
      int row = c >> 2, pos = c & 3;
      async16(Wb + (size_t)row * FFN_D + k0 + SWZ_CHUNK(row, pos) * 8, bs + c * 8);
    }
  };

  const int NT = FFN_D / 32;  // 128
  stage(0, 0);
  stage(1, 1);
  for (int t = 0; t < NT; ++t) {
    SBAR();
    if (t + 1 < NT) asm volatile("s_waitcnt vmcnt(4)" ::: "memory");
    else            asm volatile("s_waitcnt vmcnt(0)" ::: "memory");
    RBAR();
    SBAR();
    if (t + 2 < NT) stage((t + 2) % 3, t + 2);
    const _Float16* as = &smem[(t % 3) * 8192];
    const _Float16* bs = as + 4096;
    h8 af[4], bf[4];
#pragma unroll
    for (int i = 0; i < 4; ++i) {
      int row = wr + i * 16 + lrow;
      af[i] = *(const h8*)&as[row * 32 + SWZ_POS(row, lq) * 8];
    }
#pragma unroll
    for (int j = 0; j < 4; ++j) {
      int row = wc + j * 16 + lrow;
      bf[j] = *(const h8*)&bs[row * 32 + SWZ_POS(row, lq) * 8];
    }
    __builtin_amdgcn_s_setprio(1);
#pragma unroll
    for (int i = 0; i < 4; ++i)
#pragma unroll
      for (int j = 0; j < 4; ++j)
        acc[i][j] = __builtin_amdgcn_mfma_f32_16x16x32_f16(af[i], bf[j], acc[i][j], 0, 0, 0);
    __builtin_amdgcn_s_setprio(0);
  }

#pragma unroll
  for (int j = 0; j < 4; ++j) {
    int gcol = n0 + wc + j * 16 + lrow;
    float bias = b2[e * HID + gcol];
#pragma unroll
    for (int i = 0; i < 4; ++i) {
#pragma unroll
      for (int r = 0; r < 4; ++r) {
        int grow = wr + i * 16 + lq * 4 + r;
        if (grow < rows) {
          int row = row0 + grow;
          float w = pw[row];
          pairout[(size_t)row * HID + gcol] = w * (acc[i][j][r] + bias);
        }
      }
    }
  }
}

// ---------------- combine: out[t] = pairout[p0(t)] + pairout[p1(t)] ----------------
__global__ void k_combine(const float* __restrict__ pairout, const int* __restrict__ ppos,
                          float* __restrict__ out) {
  int t = blockIdx.x;
  int c = threadIdx.x;
  int p0 = ppos[2 * t];
  int p1 = ppos[2 * t + 1];
  const float4* a = (const float4*)(pairout + (size_t)p0 * HID);
  const float4* b = (const float4*)(pairout + (size_t)p1 * HID);
  float4 va = a[c];
  float4 vb = b[c];
  float4 o;
  o.x = va.x + vb.x; o.y = va.y + vb.y; o.z = va.z + vb.z; o.w = va.w + vb.w;
  ((float4*)(out + (size_t)t * HID))[c] = o;
}

extern "C" void kernel_launch(void* const* d_in, const int* in_sizes, int n_in,
                              void* d_out, int out_size, void* d_ws, size_t ws_size,
                              hipStream_t stream) {
  const float* x  = (const float*)d_in[0];
  const float* Wr = (const float*)d_in[1];
  const float* W1 = (const float*)d_in[2];
  const float* b1 = (const float*)d_in[3];
  const float* W2 = (const float*)d_in[4];
  const float* b2 = (const float*)d_in[5];
  float* out = (float*)d_out;

  uint8_t* ws = (uint8_t*)d_ws;
  int* meta    = (int*)ws;
  int* counts  = meta;        // 8
  int* cursors = meta + 8;    // 8
  int* offsets = meta + 16;   // 8
  int* nmb     = meta + 24;   // 1
  int* bexp    = meta + 32;   // 160
  int* brow0   = meta + 192;  // 160
  int* brows   = meta + 352;  // 160
  int2*   re   = (int2*)(ws + 4096);
  float2* rs   = (float2*)(ws + 69632);
  int*    ppos = (int*)(ws + 69632);             // aliases rs (dead after k_scatter)
  int*    ptok = (int*)(ws + 135168);
  float*  pw   = (float*)(ws + 201216);
  _Float16* A    = (_Float16*)(ws + 267264);     // [16512,1024]
  _Float16* W1h  = (_Float16*)(ws + 34083840);   // [8,4096,1024]
  float* pairout = (float*)(ws + 34083840);      // [16384,1024] f32, aliases W1h (dead after fc1)
  _Float16* W2h  = (_Float16*)(ws + 101192704);  // [8,1024,4096]
  _Float16* hmid = (_Float16*)(ws + 168301568);  // [16512,4096]

  hipMemsetAsync(ws, 0, 4096, stream);

  k_router<<<T_TOK / 4, 256, 0, stream>>>(x, Wr, re, rs, counts);
  k_plan<<<1, 64, 0, stream>>>(counts, offsets, cursors, nmb, bexp, brow0, brows);
  k_scatter<<<T_TOK / 256, 256, 0, stream>>>(re, rs, cursors, ptok, pw, ppos);
  k_gather<<<NPAIR / 4, 256, 0, stream>>>(x, ptok, A);
  k_cast2<<<4096, 256, 0, stream>>>(W1, W1h, W2, W2h, NE * FFN_D * HID / 4);
  k_fc1<<<dim3(FFN_D / 128, MAXMB), 256, 0, stream>>>(A, W1h, b1, hmid, nmb, bexp, brow0, brows);
  k_fc2<<<dim3(HID / 128, MAXMB), 256, 0, stream>>>(hmid, W2h, b2, pw, pairout, nmb, bexp, brow0, brows);
  k_combine<<<T_TOK, 256, 0, stream>>>(pairout, ppos, out);
}